// Round 7
// baseline (364.821 us; speedup 1.0000x reference)
//
#include <hip/hip_runtime.h>
#include <hip/hip_fp16.h>

#define NN 50000
#define NE 800000
#define C_IN 384
#define C_HID 128
#define NB 196  // ceil(NN/256)

typedef __attribute__((ext_vector_type(8))) short short8;
typedef __attribute__((ext_vector_type(4))) float f32x4;
typedef __attribute__((ext_vector_type(4))) unsigned short us4;

__device__ __forceinline__ ushort f2bf(float x) {
    uint u = __float_as_uint(x);
    uint r = (u + 0x7fffu + ((u >> 16) & 1u)) >> 16;  // RNE
    return (ushort)r;
}
__device__ __forceinline__ float bf2f(ushort b) { return __uint_as_float(((uint)b) << 16); }

// ---------------- degree count (int), 4 edges/thread ----------------
__global__ __launch_bounds__(256) void k_deg(const int* __restrict__ dst,
                                             int* __restrict__ cnt) {
    int e = (blockIdx.x * 256 + threadIdx.x) * 4;
    if (e < NE) {
        int4 d4 = *(const int4*)(dst + e);
        atomicAdd(&cnt[d4.x], 1);
        atomicAdd(&cnt[d4.y], 1);
        atomicAdd(&cnt[d4.z], 1);
        atomicAdd(&cnt[d4.w], 1);
    }
}

__global__ __launch_bounds__(256) void k_dinv(const int* __restrict__ cnt,
                                              float* __restrict__ dinv) {
    int i = blockIdx.x * 256 + threadIdx.x;
    if (i < NN) dinv[i] = rsqrtf((float)cnt[i] + 1.0f);  // +1 = self loop
}

// ---------------- hierarchical exclusive scan over NN counts ----------------
__global__ __launch_bounds__(256) void k_bsum(const int* __restrict__ cnt,
                                              int* __restrict__ bsum) {
    __shared__ int part[256];
    const int tid = threadIdx.x;
    const int i = blockIdx.x * 256 + tid;
    part[tid] = (i < NN) ? cnt[i] : 0;
    __syncthreads();
#pragma unroll
    for (int off = 128; off > 0; off >>= 1) {
        if (tid < off) part[tid] += part[tid + off];
        __syncthreads();
    }
    if (tid == 0) bsum[blockIdx.x] = part[0];
}

__global__ __launch_bounds__(256) void k_sbs(const int* __restrict__ bsum,
                                             int* __restrict__ bpre) {
    __shared__ int part[256];
    const int t = threadIdx.x;
    part[t] = (t < NB) ? bsum[t] : 0;
    __syncthreads();
#pragma unroll
    for (int off = 1; off < 256; off <<= 1) {
        int v = (t >= off) ? part[t - off] : 0;
        __syncthreads();
        part[t] += v;
        __syncthreads();
    }
    if (t < NB) bpre[t] = (t == 0) ? 0 : part[t - 1];  // exclusive
}

__global__ __launch_bounds__(256) void k_write(const int* __restrict__ cnt,
                                               const int* __restrict__ bpre,
                                               int* __restrict__ rowptr,
                                               int* __restrict__ cursor) {
    __shared__ int part[256];
    const int t = threadIdx.x;
    const int i = blockIdx.x * 256 + t;
    const int v = (i < NN) ? cnt[i] : 0;
    part[t] = v;
    __syncthreads();
#pragma unroll
    for (int off = 1; off < 256; off <<= 1) {
        int u = (t >= off) ? part[t - off] : 0;
        __syncthreads();
        part[t] += u;
        __syncthreads();
    }
    if (i < NN) {
        const int excl = bpre[blockIdx.x] + part[t] - v;
        rowptr[i] = excl;
        cursor[i] = excl;
        if (i == NN - 1) rowptr[NN] = excl + v;
    }
}

// ---------------- CSR fill: entry = (src:16 | fp16(norm):16), 4 edges/thread ----------------
__global__ __launch_bounds__(256) void k_fill(const int* __restrict__ src,
                                              const int* __restrict__ dst,
                                              const float* __restrict__ dinv,
                                              int* __restrict__ cursor,
                                              uint* __restrict__ csr) {
    int e = (blockIdx.x * 256 + threadIdx.x) * 4;
    if (e >= NE) return;
    int4 s4 = *(const int4*)(src + e);
    int4 d4 = *(const int4*)(dst + e);
    float n0 = dinv[s4.x] * dinv[d4.x];
    float n1 = dinv[s4.y] * dinv[d4.y];
    float n2 = dinv[s4.z] * dinv[d4.z];
    float n3 = dinv[s4.w] * dinv[d4.w];
    int p0 = atomicAdd(&cursor[d4.x], 1);
    int p1 = atomicAdd(&cursor[d4.y], 1);
    int p2 = atomicAdd(&cursor[d4.z], 1);
    int p3 = atomicAdd(&cursor[d4.w], 1);
    csr[p0] = ((uint)s4.x << 16) | __half_as_ushort(__float2half(n0));
    csr[p1] = ((uint)s4.y << 16) | __half_as_ushort(__float2half(n1));
    csr[p2] = ((uint)s4.z << 16) | __half_as_ushort(__float2half(n2));
    csr[p3] = ((uint)s4.w << 16) | __half_as_ushort(__float2half(n3));
}

// ---------------- W -> fragment-linear hi/lo bf16 split (once per launch) ----------------
// W is [K][128] fp32.  Wt layout: per 64-k block (32 KB = 16384 shorts):
//   hi region [0,8192): chunk (khalf,t) of 512 shorts, lane-ordered:
//     short index = (khalf*8 + t)*512 + lane*8 + j   where lane = kq*16 + fr
//     holds B[n = t*16+fr][k = blk*64 + khalf*32 + kq*8 + j]
//   lo region at +8192.
__global__ __launch_bounds__(256) void k_wconv(const float* __restrict__ W,
                                               ushort* __restrict__ Wt,
                                               int K) {
    int i = blockIdx.x * 256 + threadIdx.x;
    if (i < K * C_HID) {
        int k = i >> 7, n = i & 127;  // N = 128
        float w = W[i];
        ushort h = f2bf(w);
        ushort l = f2bf(w - bf2f(h));
        int blk = k >> 6, khalf = (k >> 5) & 1, kq = (k >> 3) & 3, j = k & 7;
        int t = n >> 4, fr = n & 15, lane = kq * 16 + fr;
        size_t off = (size_t)blk * 16384 + (size_t)((khalf * 8 + t) * 64 + lane) * 8 + j;
        Wt[off] = h;
        Wt[off + 8192] = l;
    }
}

// ---------------- split-bf16 MFMA GEMM (A direct-to-reg, conflict-free B LDS) ----------------
template <bool IN_RELU_BIAS, bool OUT_BIAS>
__global__ __launch_bounds__(256) void k_gemm_mfma(const float* __restrict__ X,
                                                   const ushort* __restrict__ Wt,
                                                   const float* __restrict__ bin,
                                                   const float* __restrict__ bout,
                                                   const float* __restrict__ dinv,
                                                   ushort* __restrict__ out_main,
                                                   float* __restrict__ out_self,
                                                   int K) {
    __shared__ short8 Bs8[2048];  // 32 KB, one 64-k block of W (hi 16K + lo 16K)

    const int tid = threadIdx.x;
    const int bm = blockIdx.x * 64;
    const int wv = tid >> 6;      // wave -> m rows [bm+wv*16, +16)
    const int lane = tid & 63;
    const int fr = lane & 15;
    const int kq = lane >> 4;

    int row = bm + wv * 16 + fr;
    if (row >= NN) row = NN - 1;  // clamp (stores guarded)
    const float* xrow = X + (size_t)row * K + kq * 8;
    const short8* Wt8 = (const short8*)Wt;

    f32x4 acc[8];
#pragma unroll
    for (int t = 0; t < 8; ++t) acc[t] = (f32x4){0.f, 0.f, 0.f, 0.f};

    for (int k0 = 0; k0 < K; k0 += 64) {
        // ---- A: direct global -> regs ----
        const float* ap = xrow + k0;
        float4 xa0 = *(const float4*)(ap);
        float4 xa1 = *(const float4*)(ap + 4);
        float4 xb0 = *(const float4*)(ap + 32);
        float4 xb1 = *(const float4*)(ap + 36);

        // ---- B: straight 32 KB copy to regs (contiguous, coalesced) ----
        short8 tmp[8];
        const short8* gB = Wt8 + (size_t)(k0 >> 6) * 2048;
#pragma unroll
        for (int i = 0; i < 8; ++i) tmp[i] = gB[i * 256 + tid];

        // ---- convert A to hi/lo bf16 (truncation split) ----
        float xv[16] = {xa0.x, xa0.y, xa0.z, xa0.w, xa1.x, xa1.y, xa1.z, xa1.w,
                        xb0.x, xb0.y, xb0.z, xb0.w, xb1.x, xb1.y, xb1.z, xb1.w};
        if (IN_RELU_BIAS) {
            const float* bp = bin + k0 + kq * 8;
            float4 b0 = *(const float4*)(bp);
            float4 b1 = *(const float4*)(bp + 4);
            float4 b2 = *(const float4*)(bp + 32);
            float4 b3 = *(const float4*)(bp + 36);
            const float bb[16] = {b0.x, b0.y, b0.z, b0.w, b1.x, b1.y, b1.z, b1.w,
                                  b2.x, b2.y, b2.z, b2.w, b3.x, b3.y, b3.z, b3.w};
#pragma unroll
            for (int j = 0; j < 16; ++j) xv[j] = fmaxf(xv[j] + bb[j], 0.f);
        }
        union { ushort u[8]; short8 v; } ah0, al0, ah1, al1;
#pragma unroll
        for (int j = 0; j < 8; ++j) {
            uint u = __float_as_uint(xv[j]);
            ah0.u[j] = (ushort)(u >> 16);
            al0.u[j] = (ushort)(__float_as_uint(xv[j] - __uint_as_float(u & 0xffff0000u)) >> 16);
            uint w = __float_as_uint(xv[8 + j]);
            ah1.u[j] = (ushort)(w >> 16);
            al1.u[j] = (ushort)(__float_as_uint(xv[8 + j] - __uint_as_float(w & 0xffff0000u)) >> 16);
        }

        __syncthreads();  // previous iter's Bs readers done
#pragma unroll
        for (int i = 0; i < 8; ++i) Bs8[i * 256 + tid] = tmp[i];
        __syncthreads();  // Bs visible

        // ---- MFMA: 48 per wave per iter, lane-contiguous b128 LDS reads ----
#pragma unroll
        for (int t = 0; t < 8; ++t) {
            const short8 bh0 = Bs8[t * 64 + lane];
            const short8 bl0 = Bs8[1024 + t * 64 + lane];
            const short8 bh1 = Bs8[(8 + t) * 64 + lane];
            const short8 bl1 = Bs8[1024 + (8 + t) * 64 + lane];
            acc[t] = __builtin_amdgcn_mfma_f32_16x16x32_bf16(ah0.v, bh0, acc[t], 0, 0, 0);
            acc[t] = __builtin_amdgcn_mfma_f32_16x16x32_bf16(ah0.v, bl0, acc[t], 0, 0, 0);
            acc[t] = __builtin_amdgcn_mfma_f32_16x16x32_bf16(al0.v, bh0, acc[t], 0, 0, 0);
            acc[t] = __builtin_amdgcn_mfma_f32_16x16x32_bf16(ah1.v, bh1, acc[t], 0, 0, 0);
            acc[t] = __builtin_amdgcn_mfma_f32_16x16x32_bf16(ah1.v, bl1, acc[t], 0, 0, 0);
            acc[t] = __builtin_amdgcn_mfma_f32_16x16x32_bf16(al1.v, bh1, acc[t], 0, 0, 0);
        }
    }

    // ---- epilogue: D(lane,reg): m = bm + wv*16 + kq*4 + r, n = t*16 + fr ----
#pragma unroll
    for (int r = 0; r < 4; ++r) {
        const int m = bm + wv * 16 + kq * 4 + r;
        if (m < NN) {
            const float dv = dinv[m];
            const float d2 = dv * dv;
            ushort* om = out_main + (size_t)m * C_HID;
            float* os = out_self + (size_t)m * C_HID;
#pragma unroll
            for (int t = 0; t < 8; ++t) {
                const int n = t * 16 + fr;
                const float v = acc[t][r];
                om[n] = f2bf(v);
                os[n] = v * d2 + (OUT_BIAS ? bout[n] : 0.f);
            }
        }
    }
}

// ---------------- CSR gather: out[d] = init(out[d]) + sum_e bf16(h[src_e])*norm_e ----------------
// 32 lanes per dst node (8 nodes / block), lane owns 4 channels.  4-deep load MLP.
// csr entry: (src:16 | fp16 norm:16), norm = dinv[src]*dinv[dst] premultiplied.
__global__ __launch_bounds__(256) void k_gather(const ushort* __restrict__ h,
                                                const int* __restrict__ rowptr,
                                                const uint* __restrict__ csr,
                                                float* __restrict__ out) {
    const int tid = threadIdx.x;
    const int node = blockIdx.x * 8 + (tid >> 5);
    if (node >= NN) return;
    const int lane = tid & 31;
    const int c = lane * 4;
    const int beg = rowptr[node];
    const int end = rowptr[node + 1];

    float4 acc = *(const float4*)(out + (size_t)node * C_HID + c);  // self-loop init from GEMM epilogue

    for (int j0 = beg; j0 < end; j0 += 32) {
        const int n = end - j0;
        uint myE = 0;
        if (lane < n) myE = csr[j0 + lane];
        const int m = n < 32 ? n : 32;
        int jj = 0;
        for (; jj + 4 <= m; jj += 4) {
            const uint e0 = (uint)__shfl((int)myE, jj + 0, 32);
            const uint e1 = (uint)__shfl((int)myE, jj + 1, 32);
            const uint e2 = (uint)__shfl((int)myE, jj + 2, 32);
            const uint e3 = (uint)__shfl((int)myE, jj + 3, 32);
            const us4 u0 = *(const us4*)(h + (size_t)(e0 >> 16) * C_HID + c);
            const us4 u1 = *(const us4*)(h + (size_t)(e1 >> 16) * C_HID + c);
            const us4 u2 = *(const us4*)(h + (size_t)(e2 >> 16) * C_HID + c);
            const us4 u3 = *(const us4*)(h + (size_t)(e3 >> 16) * C_HID + c);
            const float n0 = __half2float(__ushort_as_half((ushort)(e0 & 0xffffu)));
            const float n1 = __half2float(__ushort_as_half((ushort)(e1 & 0xffffu)));
            const float n2 = __half2float(__ushort_as_half((ushort)(e2 & 0xffffu)));
            const float n3 = __half2float(__ushort_as_half((ushort)(e3 & 0xffffu)));
            acc.x = fmaf(bf2f(u0[0]), n0, acc.x);
            acc.y = fmaf(bf2f(u0[1]), n0, acc.y);
            acc.z = fmaf(bf2f(u0[2]), n0, acc.z);
            acc.w = fmaf(bf2f(u0[3]), n0, acc.w);
            acc.x = fmaf(bf2f(u1[0]), n1, acc.x);
            acc.y = fmaf(bf2f(u1[1]), n1, acc.y);
            acc.z = fmaf(bf2f(u1[2]), n1, acc.z);
            acc.w = fmaf(bf2f(u1[3]), n1, acc.w);
            acc.x = fmaf(bf2f(u2[0]), n2, acc.x);
            acc.y = fmaf(bf2f(u2[1]), n2, acc.y);
            acc.z = fmaf(bf2f(u2[2]), n2, acc.z);
            acc.w = fmaf(bf2f(u2[3]), n2, acc.w);
            acc.x = fmaf(bf2f(u3[0]), n3, acc.x);
            acc.y = fmaf(bf2f(u3[1]), n3, acc.y);
            acc.z = fmaf(bf2f(u3[2]), n3, acc.z);
            acc.w = fmaf(bf2f(u3[3]), n3, acc.w);
        }
        for (; jj < m; ++jj) {
            const uint ev = (uint)__shfl((int)myE, jj, 32);
            const us4 u = *(const us4*)(h + (size_t)(ev >> 16) * C_HID + c);
            const float nw = __half2float(__ushort_as_half((ushort)(ev & 0xffffu)));
            acc.x = fmaf(bf2f(u[0]), nw, acc.x);
            acc.y = fmaf(bf2f(u[1]), nw, acc.y);
            acc.z = fmaf(bf2f(u[2]), nw, acc.z);
            acc.w = fmaf(bf2f(u[3]), nw, acc.w);
        }
    }
    *(float4*)(out + (size_t)node * C_HID + c) = acc;
}

extern "C" void kernel_launch(void* const* d_in, const int* in_sizes, int n_in,
                              void* d_out, int out_size, void* d_ws, size_t ws_size,
                              hipStream_t stream) {
    const float* x = (const float*)d_in[0];
    const int* ei = (const int*)d_in[1];
    const float* W1 = (const float*)d_in[2];
    const float* b1 = (const float*)d_in[3];
    const float* W2 = (const float*)d_in[4];
    const float* b2 = (const float*)d_in[5];
    float* out = (float*)d_out;

    const int* src = ei;
    const int* dst = ei + NE;

    // workspace layout (4-byte units)
    int* cnt = (int*)d_ws;                       // 50048
    int* rowptr = cnt + 50048;                   // 50064 (NN+1)
    int* cursor = rowptr + 50064;                // 50048
    float* dinv = (float*)(cursor + 50048);      // 50048
    int* bsum = (int*)(dinv + 50048);            // 256
    int* bpre = bsum + 256;                      // 256
    ushort* Wt1 = (ushort*)(bpre + 256);         // 98304 shorts (frag-linear hi+lo)
    ushort* Wt2 = Wt1 + 98304;                   // 32768 shorts
    uint* csr = (uint*)(Wt2 + 32768);            // NE uints
    ushort* A_bf = (ushort*)(csr + NE);          // NN*128 shorts (h bf16)
    float* B = (float*)(A_bf + (size_t)NN * C_HID);  // NN*128 fp32 (agg buffer)

    hipMemsetAsync(cnt, 0, NN * sizeof(int), stream);
    k_wconv<<<(C_IN * C_HID + 255) / 256, 256, 0, stream>>>(W1, Wt1, C_IN);
    k_wconv<<<(C_HID * C_HID + 255) / 256, 256, 0, stream>>>(W2, Wt2, C_HID);
    k_deg<<<(NE / 4 + 255) / 256, 256, 0, stream>>>(dst, cnt);
    k_dinv<<<NB, 256, 0, stream>>>(cnt, dinv);
    k_bsum<<<NB, 256, 0, stream>>>(cnt, bsum);
    k_sbs<<<1, 256, 0, stream>>>(bsum, bpre);
    k_write<<<NB, 256, 0, stream>>>(cnt, bpre, rowptr, cursor);
    k_fill<<<(NE / 4 + 255) / 256, 256, 0, stream>>>(src, dst, dinv, cursor, csr);

    const int gblocks = (NN + 63) / 64;
    const int agblocks = (NN + 7) / 8;
    // layer 1: h1 = x@W1 -> A_bf (bf16) ;  B = h1*dinv^2 (fp32 self-loop init)
    k_gemm_mfma<false, false><<<gblocks, 256, 0, stream>>>(x, Wt1, nullptr, nullptr, dinv, A_bf, B, C_IN);
    // B += gather(h1)
    k_gather<<<agblocks, 256, 0, stream>>>(A_bf, rowptr, csr, B);
    // layer 2: h2 = relu(B + b1)@W2 -> A_bf ; out = h2*dinv^2 + b2 (self-loop init)
    k_gemm_mfma<true, true><<<gblocks, 256, 0, stream>>>(B, Wt2, b1, b2, dinv, A_bf, out, C_HID);
    // out += gather(h2)
    k_gather<<<agblocks, 256, 0, stream>>>(A_bf, rowptr, csr, out);
}

// Round 8
// 339.263 us; speedup vs baseline: 1.0753x; 1.0753x over previous
//
#include <hip/hip_runtime.h>
#include <hip/hip_fp16.h>

#define NN 50000
#define NE 800000
#define C_IN 384
#define C_HID 128
#define NB 196    // ceil(NN/256)
#define CHK 128   // edge chunks
#define ECH 6250  // edges per chunk (128*6250 = 800000)
#define NBKT 128  // dst buckets
#define BSTR 392  // dst stride per bucket (128*392 = 50176 >= NN)

typedef __attribute__((ext_vector_type(8))) short short8;
typedef __attribute__((ext_vector_type(4))) float f32x4;
typedef __attribute__((ext_vector_type(4))) unsigned short us4;

__device__ __forceinline__ ushort f2bf(float x) {
    uint u = __float_as_uint(x);
    uint r = (u + 0x7fffu + ((u >> 16) & 1u)) >> 16;  // RNE
    return (ushort)r;
}
__device__ __forceinline__ float bf2f(ushort b) { return __uint_as_float(((uint)b) << 16); }

// ---------------- degree count (int) ----------------
__global__ __launch_bounds__(256) void k_deg(const int* __restrict__ dst,
                                             int* __restrict__ cnt) {
    int i = blockIdx.x * 256 + threadIdx.x;
    if (i < NE) atomicAdd(&cnt[dst[i]], 1);
}

__global__ __launch_bounds__(256) void k_dinv(const int* __restrict__ cnt,
                                              float* __restrict__ dinv) {
    int i = blockIdx.x * 256 + threadIdx.x;
    if (i < NN) dinv[i] = rsqrtf((float)cnt[i] + 1.0f);  // +1 = self loop
}

// ---------------- hierarchical exclusive scan over NN counts -> rowptr ----------------
__global__ __launch_bounds__(256) void k_bsum(const int* __restrict__ cnt,
                                              int* __restrict__ bsum) {
    __shared__ int part[256];
    const int tid = threadIdx.x;
    const int i = blockIdx.x * 256 + tid;
    part[tid] = (i < NN) ? cnt[i] : 0;
    __syncthreads();
#pragma unroll
    for (int off = 128; off > 0; off >>= 1) {
        if (tid < off) part[tid] += part[tid + off];
        __syncthreads();
    }
    if (tid == 0) bsum[blockIdx.x] = part[0];
}

__global__ __launch_bounds__(256) void k_sbs(const int* __restrict__ bsum,
                                             int* __restrict__ bpre) {
    __shared__ int part[256];
    const int t = threadIdx.x;
    part[t] = (t < NB) ? bsum[t] : 0;
    __syncthreads();
#pragma unroll
    for (int off = 1; off < 256; off <<= 1) {
        int v = (t >= off) ? part[t - off] : 0;
        __syncthreads();
        part[t] += v;
        __syncthreads();
    }
    if (t < NB) bpre[t] = (t == 0) ? 0 : part[t - 1];  // exclusive
}

__global__ __launch_bounds__(256) void k_write(const int* __restrict__ cnt,
                                               const int* __restrict__ bpre,
                                               int* __restrict__ rowptr) {
    __shared__ int part[256];
    const int t = threadIdx.x;
    const int i = blockIdx.x * 256 + t;
    const int v = (i < NN) ? cnt[i] : 0;
    part[t] = v;
    __syncthreads();
#pragma unroll
    for (int off = 1; off < 256; off <<= 1) {
        int u = (t >= off) ? part[t - off] : 0;
        __syncthreads();
        part[t] += u;
        __syncthreads();
    }
    if (i < NN) {
        const int excl = bpre[blockIdx.x] + part[t] - v;
        rowptr[i] = excl;
        if (i == NN - 1) rowptr[NN] = excl + v;
    }
}

// ---------------- bucket pipeline: hist -> scan -> binscat -> binfill ----------------
// k_hist: per-(chunk,bucket) counts, bucket-major output histT[b*CHK + chunk]
__global__ __launch_bounds__(256) void k_hist(const int* __restrict__ dst,
                                              int* __restrict__ histT) {
    __shared__ int h[NBKT];
    const int tid = threadIdx.x;
    if (tid < NBKT) h[tid] = 0;
    __syncthreads();
    const int base = blockIdx.x * ECH;
    for (int i = base + tid; i < base + ECH; i += 256)
        atomicAdd(&h[(uint)dst[i] / BSTR], 1);
    __syncthreads();
    if (tid < NBKT) histT[tid * CHK + blockIdx.x] = h[tid];
}

// k_hscan: exclusive scan of histT[NBKT*CHK = 16384] -> histS (mid offsets)
__global__ __launch_bounds__(1024) void k_hscan(const int* __restrict__ histT,
                                                int* __restrict__ histS) {
    __shared__ int part[1024];
    const int t = threadIdx.x;
    const int base = t * 16;
    int loc[16];
    int s = 0;
#pragma unroll
    for (int i = 0; i < 16; ++i) {
        loc[i] = histT[base + i];
        s += loc[i];
    }
    part[t] = s;
    __syncthreads();
    for (int off = 1; off < 1024; off <<= 1) {
        int v = (t >= off) ? part[t - off] : 0;
        __syncthreads();
        part[t] += v;
        __syncthreads();
    }
    int run = (t == 0) ? 0 : part[t - 1];
#pragma unroll
    for (int i = 0; i < 16; ++i) {
        histS[base + i] = run;
        run += loc[i];
    }
}

// k_binscat: chunks re-read edges, write (dst, payload) to bucket-major mid[]
// payload = (src:16 | fp16(norm):16), norm = dinv[src]*dinv[dst]
__global__ __launch_bounds__(256) void k_binscat(const int* __restrict__ src,
                                                 const int* __restrict__ dst,
                                                 const float* __restrict__ dinv,
                                                 const int* __restrict__ histS,
                                                 uint2* __restrict__ mid) {
    __shared__ int cur[NBKT];
    const int tid = threadIdx.x;
    if (tid < NBKT) cur[tid] = histS[tid * CHK + blockIdx.x];
    __syncthreads();
    const int base = blockIdx.x * ECH;
    for (int i = base + tid; i < base + ECH; i += 256) {
        const int s = src[i];
        const int d = dst[i];
        const float norm = dinv[s] * dinv[d];
        const int p = atomicAdd(&cur[(uint)d / BSTR], 1);
        mid[p] = make_uint2((uint)d, ((uint)s << 16) | __half_as_ushort(__float2half(norm)));
    }
}

// k_binfill: one block per bucket; scatter confined to ~25 KB csr window
__global__ __launch_bounds__(256) void k_binfill(const uint2* __restrict__ mid,
                                                 const int* __restrict__ histS,
                                                 const int* __restrict__ rowptr,
                                                 uint* __restrict__ csr) {
    __shared__ int cur[BSTR];
    const int tid = threadIdx.x;
    const int b = blockIdx.x;
    for (int j = tid; j < BSTR; j += 256) {
        const int idx = b * BSTR + j;
        cur[j] = (idx < NN) ? rowptr[idx] : 0;
    }
    __syncthreads();
    const int lo = histS[b * CHK];
    const int hi = (b < NBKT - 1) ? histS[(b + 1) * CHK] : NE;
    for (int e = lo + tid; e < hi; e += 256) {
        const uint2 u = mid[e];
        const int p = atomicAdd(&cur[u.x - (uint)b * BSTR], 1);
        csr[p] = u.y;
    }
}

// ---------------- W -> fragment-linear hi/lo bf16 split (once per launch) ----------------
__global__ __launch_bounds__(256) void k_wconv(const float* __restrict__ W,
                                               ushort* __restrict__ Wt,
                                               int K) {
    int i = blockIdx.x * 256 + threadIdx.x;
    if (i < K * C_HID) {
        int k = i >> 7, n = i & 127;  // N = 128
        float w = W[i];
        ushort h = f2bf(w);
        ushort l = f2bf(w - bf2f(h));
        int blk = k >> 6, khalf = (k >> 5) & 1, kq = (k >> 3) & 3, j = k & 7;
        int t = n >> 4, fr = n & 15, lane = kq * 16 + fr;
        size_t off = (size_t)blk * 16384 + (size_t)((khalf * 8 + t) * 64 + lane) * 8 + j;
        Wt[off] = h;
        Wt[off + 8192] = l;
    }
}

// ---------------- split-bf16 MFMA GEMM (A direct-to-reg, conflict-free B LDS) ----------------
template <bool IN_RELU_BIAS, bool OUT_BIAS>
__global__ __launch_bounds__(256) void k_gemm_mfma(const float* __restrict__ X,
                                                   const ushort* __restrict__ Wt,
                                                   const float* __restrict__ bin,
                                                   const float* __restrict__ bout,
                                                   const float* __restrict__ dinv,
                                                   ushort* __restrict__ out_main,
                                                   float* __restrict__ out_self,
                                                   int K) {
    __shared__ short8 Bs8[2048];  // 32 KB, one 64-k block of W (hi 16K + lo 16K)

    const int tid = threadIdx.x;
    const int bm = blockIdx.x * 64;
    const int wv = tid >> 6;
    const int lane = tid & 63;
    const int fr = lane & 15;
    const int kq = lane >> 4;

    int row = bm + wv * 16 + fr;
    if (row >= NN) row = NN - 1;  // clamp (stores guarded)
    const float* xrow = X + (size_t)row * K + kq * 8;
    const short8* Wt8 = (const short8*)Wt;

    f32x4 acc[8];
#pragma unroll
    for (int t = 0; t < 8; ++t) acc[t] = (f32x4){0.f, 0.f, 0.f, 0.f};

    for (int k0 = 0; k0 < K; k0 += 64) {
        const float* ap = xrow + k0;
        float4 xa0 = *(const float4*)(ap);
        float4 xa1 = *(const float4*)(ap + 4);
        float4 xb0 = *(const float4*)(ap + 32);
        float4 xb1 = *(const float4*)(ap + 36);

        short8 tmp[8];
        const short8* gB = Wt8 + (size_t)(k0 >> 6) * 2048;
#pragma unroll
        for (int i = 0; i < 8; ++i) tmp[i] = gB[i * 256 + tid];

        float xv[16] = {xa0.x, xa0.y, xa0.z, xa0.w, xa1.x, xa1.y, xa1.z, xa1.w,
                        xb0.x, xb0.y, xb0.z, xb0.w, xb1.x, xb1.y, xb1.z, xb1.w};
        if (IN_RELU_BIAS) {
            const float* bp = bin + k0 + kq * 8;
            float4 b0 = *(const float4*)(bp);
            float4 b1 = *(const float4*)(bp + 4);
            float4 b2 = *(const float4*)(bp + 32);
            float4 b3 = *(const float4*)(bp + 36);
            const float bb[16] = {b0.x, b0.y, b0.z, b0.w, b1.x, b1.y, b1.z, b1.w,
                                  b2.x, b2.y, b2.z, b2.w, b3.x, b3.y, b3.z, b3.w};
#pragma unroll
            for (int j = 0; j < 16; ++j) xv[j] = fmaxf(xv[j] + bb[j], 0.f);
        }
        union { ushort u[8]; short8 v; } ah0, al0, ah1, al1;
#pragma unroll
        for (int j = 0; j < 8; ++j) {
            uint u = __float_as_uint(xv[j]);
            ah0.u[j] = (ushort)(u >> 16);
            al0.u[j] = (ushort)(__float_as_uint(xv[j] - __uint_as_float(u & 0xffff0000u)) >> 16);
            uint w = __float_as_uint(xv[8 + j]);
            ah1.u[j] = (ushort)(w >> 16);
            al1.u[j] = (ushort)(__float_as_uint(xv[8 + j] - __uint_as_float(w & 0xffff0000u)) >> 16);
        }

        __syncthreads();
#pragma unroll
        for (int i = 0; i < 8; ++i) Bs8[i * 256 + tid] = tmp[i];
        __syncthreads();

#pragma unroll
        for (int t = 0; t < 8; ++t) {
            const short8 bh0 = Bs8[t * 64 + lane];
            const short8 bl0 = Bs8[1024 + t * 64 + lane];
            const short8 bh1 = Bs8[(8 + t) * 64 + lane];
            const short8 bl1 = Bs8[1024 + (8 + t) * 64 + lane];
            acc[t] = __builtin_amdgcn_mfma_f32_16x16x32_bf16(ah0.v, bh0, acc[t], 0, 0, 0);
            acc[t] = __builtin_amdgcn_mfma_f32_16x16x32_bf16(ah0.v, bl0, acc[t], 0, 0, 0);
            acc[t] = __builtin_amdgcn_mfma_f32_16x16x32_bf16(al0.v, bh0, acc[t], 0, 0, 0);
            acc[t] = __builtin_amdgcn_mfma_f32_16x16x32_bf16(ah1.v, bh1, acc[t], 0, 0, 0);
            acc[t] = __builtin_amdgcn_mfma_f32_16x16x32_bf16(ah1.v, bl1, acc[t], 0, 0, 0);
            acc[t] = __builtin_amdgcn_mfma_f32_16x16x32_bf16(al1.v, bh1, acc[t], 0, 0, 0);
        }
    }

#pragma unroll
    for (int r = 0; r < 4; ++r) {
        const int m = bm + wv * 16 + kq * 4 + r;
        if (m < NN) {
            const float dv = dinv[m];
            const float d2 = dv * dv;
            ushort* om = out_main + (size_t)m * C_HID;
            float* os = out_self + (size_t)m * C_HID;
#pragma unroll
            for (int t = 0; t < 8; ++t) {
                const int n = t * 16 + fr;
                const float v = acc[t][r];
                om[n] = f2bf(v);
                os[n] = v * d2 + (OUT_BIAS ? bout[n] : 0.f);
            }
        }
    }
}

// ---------------- CSR gather: out[d] = init(out[d]) + sum_e bf16(h[src_e])*norm_e ----------------
__global__ __launch_bounds__(256) void k_gather(const ushort* __restrict__ h,
                                                const int* __restrict__ rowptr,
                                                const uint* __restrict__ csr,
                                                float* __restrict__ out) {
    const int tid = threadIdx.x;
    const int node = blockIdx.x * 8 + (tid >> 5);
    if (node >= NN) return;
    const int lane = tid & 31;
    const int c = lane * 4;
    const int beg = rowptr[node];
    const int end = rowptr[node + 1];

    float4 acc = *(const float4*)(out + (size_t)node * C_HID + c);  // self-loop init

    for (int j0 = beg; j0 < end; j0 += 32) {
        const int n = end - j0;
        uint myE = 0;
        if (lane < n) myE = csr[j0 + lane];
        const int m = n < 32 ? n : 32;
        int jj = 0;
        for (; jj + 4 <= m; jj += 4) {
            const uint e0 = (uint)__shfl((int)myE, jj + 0, 32);
            const uint e1 = (uint)__shfl((int)myE, jj + 1, 32);
            const uint e2 = (uint)__shfl((int)myE, jj + 2, 32);
            const uint e3 = (uint)__shfl((int)myE, jj + 3, 32);
            const us4 u0 = *(const us4*)(h + (size_t)(e0 >> 16) * C_HID + c);
            const us4 u1 = *(const us4*)(h + (size_t)(e1 >> 16) * C_HID + c);
            const us4 u2 = *(const us4*)(h + (size_t)(e2 >> 16) * C_HID + c);
            const us4 u3 = *(const us4*)(h + (size_t)(e3 >> 16) * C_HID + c);
            const float n0 = __half2float(__ushort_as_half((ushort)(e0 & 0xffffu)));
            const float n1 = __half2float(__ushort_as_half((ushort)(e1 & 0xffffu)));
            const float n2 = __half2float(__ushort_as_half((ushort)(e2 & 0xffffu)));
            const float n3 = __half2float(__ushort_as_half((ushort)(e3 & 0xffffu)));
            acc.x = fmaf(bf2f(u0[0]), n0, acc.x);
            acc.y = fmaf(bf2f(u0[1]), n0, acc.y);
            acc.z = fmaf(bf2f(u0[2]), n0, acc.z);
            acc.w = fmaf(bf2f(u0[3]), n0, acc.w);
            acc.x = fmaf(bf2f(u1[0]), n1, acc.x);
            acc.y = fmaf(bf2f(u1[1]), n1, acc.y);
            acc.z = fmaf(bf2f(u1[2]), n1, acc.z);
            acc.w = fmaf(bf2f(u1[3]), n1, acc.w);
            acc.x = fmaf(bf2f(u2[0]), n2, acc.x);
            acc.y = fmaf(bf2f(u2[1]), n2, acc.y);
            acc.z = fmaf(bf2f(u2[2]), n2, acc.z);
            acc.w = fmaf(bf2f(u2[3]), n2, acc.w);
            acc.x = fmaf(bf2f(u3[0]), n3, acc.x);
            acc.y = fmaf(bf2f(u3[1]), n3, acc.y);
            acc.z = fmaf(bf2f(u3[2]), n3, acc.z);
            acc.w = fmaf(bf2f(u3[3]), n3, acc.w);
        }
        for (; jj < m; ++jj) {
            const uint ev = (uint)__shfl((int)myE, jj, 32);
            const us4 u = *(const us4*)(h + (size_t)(ev >> 16) * C_HID + c);
            const float nw = __half2float(__ushort_as_half((ushort)(ev & 0xffffu)));
            acc.x = fmaf(bf2f(u[0]), nw, acc.x);
            acc.y = fmaf(bf2f(u[1]), nw, acc.y);
            acc.z = fmaf(bf2f(u[2]), nw, acc.z);
            acc.w = fmaf(bf2f(u[3]), nw, acc.w);
        }
    }
    *(float4*)(out + (size_t)node * C_HID + c) = acc;
}

extern "C" void kernel_launch(void* const* d_in, const int* in_sizes, int n_in,
                              void* d_out, int out_size, void* d_ws, size_t ws_size,
                              hipStream_t stream) {
    const float* x = (const float*)d_in[0];
    const int* ei = (const int*)d_in[1];
    const float* W1 = (const float*)d_in[2];
    const float* b1 = (const float*)d_in[3];
    const float* W2 = (const float*)d_in[4];
    const float* b2 = (const float*)d_in[5];
    float* out = (float*)d_out;

    const int* src = ei;
    const int* dst = ei + NE;

    // workspace layout (4-byte units)
    int* cnt = (int*)d_ws;                       // 50048
    int* rowptr = cnt + 50048;                   // 50064 (NN+1)
    float* dinv = (float*)(rowptr + 50064);      // 50048
    int* bsum = (int*)(dinv + 50048);            // 256
    int* bpre = bsum + 256;                      // 256
    int* histT = bpre + 256;                     // 16384
    int* histS = histT + 16384;                  // 16384
    ushort* Wt1 = (ushort*)(histS + 16384);      // 98304 shorts (frag-linear hi+lo)
    ushort* Wt2 = Wt1 + 98304;                   // 32768 shorts
    uint* csr = (uint*)(Wt2 + 32768);            // NE uints
    uint2* mid = (uint2*)(csr + NE);             // NE uint2
    ushort* A_bf = (ushort*)(mid + NE);          // NN*128 shorts (h bf16)
    float* B = (float*)(A_bf + (size_t)NN * C_HID);  // NN*128 fp32 (agg buffer)

    hipMemsetAsync(cnt, 0, NN * sizeof(int), stream);
    k_wconv<<<(C_IN * C_HID + 255) / 256, 256, 0, stream>>>(W1, Wt1, C_IN);
    k_wconv<<<(C_HID * C_HID + 255) / 256, 256, 0, stream>>>(W2, Wt2, C_HID);
    k_deg<<<(NE + 255) / 256, 256, 0, stream>>>(dst, cnt);
    k_dinv<<<NB, 256, 0, stream>>>(cnt, dinv);
    k_bsum<<<NB, 256, 0, stream>>>(cnt, bsum);
    k_sbs<<<1, 256, 0, stream>>>(bsum, bpre);
    k_write<<<NB, 256, 0, stream>>>(cnt, bpre, rowptr);
    k_hist<<<CHK, 256, 0, stream>>>(dst, histT);
    k_hscan<<<1, 1024, 0, stream>>>(histT, histS);
    k_binscat<<<CHK, 256, 0, stream>>>(src, dst, dinv, histS, mid);
    k_binfill<<<NBKT, 256, 0, stream>>>(mid, histS, rowptr, csr);

    const int gblocks = (NN + 63) / 64;
    const int agblocks = (NN + 7) / 8;
    // layer 1: h1 = x@W1 -> A_bf (bf16) ;  B = h1*dinv^2 (fp32 self-loop init)
    k_gemm_mfma<false, false><<<gblocks, 256, 0, stream>>>(x, Wt1, nullptr, nullptr, dinv, A_bf, B, C_IN);
    // B += gather(h1)
    k_gather<<<agblocks, 256, 0, stream>>>(A_bf, rowptr, csr, B);
    // layer 2: h2 = relu(B + b1)@W2 -> A_bf ; out = h2*dinv^2 + b2 (self-loop init)
    k_gemm_mfma<true, true><<<gblocks, 256, 0, stream>>>(B, Wt2, b1, b2, dinv, A_bf, out, C_HID);
    // out += gather(h2)
    k_gather<<<agblocks, 256, 0, stream>>>(A_bf, rowptr, csr, out);
}

// Round 9
// 318.130 us; speedup vs baseline: 1.1468x; 1.0664x over previous
//
#include <hip/hip_runtime.h>
#include <hip/hip_fp16.h>

#define NN 50000
#define NE 800000
#define C_IN 384
#define C_HID 128
#define NB 196    // ceil(NN/256)
#define CHK 128   // edge chunks
#define ECH 6250  // edges per chunk (128*6250 = 800000)
#define NBKT 128  // dst buckets
#define BSTR 392  // dst stride per bucket (128*392 = 50176 >= NN)

typedef __attribute__((ext_vector_type(8))) short short8;
typedef __attribute__((ext_vector_type(4))) float f32x4;
typedef __attribute__((ext_vector_type(4))) unsigned short us4;

__device__ __forceinline__ ushort f2bf(float x) {
    uint u = __float_as_uint(x);
    uint r = (u + 0x7fffu + ((u >> 16) & 1u)) >> 16;  // RNE
    return (ushort)r;
}
__device__ __forceinline__ float bf2f(ushort b) { return __uint_as_float(((uint)b) << 16); }

__global__ __launch_bounds__(256) void k_dinv(const int* __restrict__ cnt,
                                              float* __restrict__ dinv) {
    int i = blockIdx.x * 256 + threadIdx.x;
    if (i < NN) dinv[i] = rsqrtf((float)cnt[i] + 1.0f);  // +1 = self loop
}

// ---------------- hierarchical exclusive scan over NN counts -> rowptr ----------------
__global__ __launch_bounds__(256) void k_bsum(const int* __restrict__ cnt,
                                              int* __restrict__ bsum) {
    __shared__ int part[256];
    const int tid = threadIdx.x;
    const int i = blockIdx.x * 256 + tid;
    part[tid] = (i < NN) ? cnt[i] : 0;
    __syncthreads();
#pragma unroll
    for (int off = 128; off > 0; off >>= 1) {
        if (tid < off) part[tid] += part[tid + off];
        __syncthreads();
    }
    if (tid == 0) bsum[blockIdx.x] = part[0];
}

__global__ __launch_bounds__(256) void k_sbs(const int* __restrict__ bsum,
                                             int* __restrict__ bpre) {
    __shared__ int part[256];
    const int t = threadIdx.x;
    part[t] = (t < NB) ? bsum[t] : 0;
    __syncthreads();
#pragma unroll
    for (int off = 1; off < 256; off <<= 1) {
        int v = (t >= off) ? part[t - off] : 0;
        __syncthreads();
        part[t] += v;
        __syncthreads();
    }
    if (t < NB) bpre[t] = (t == 0) ? 0 : part[t - 1];  // exclusive
}

__global__ __launch_bounds__(256) void k_write(const int* __restrict__ cnt,
                                               const int* __restrict__ bpre,
                                               int* __restrict__ rowptr) {
    __shared__ int part[256];
    const int t = threadIdx.x;
    const int i = blockIdx.x * 256 + t;
    const int v = (i < NN) ? cnt[i] : 0;
    part[t] = v;
    __syncthreads();
#pragma unroll
    for (int off = 1; off < 256; off <<= 1) {
        int u = (t >= off) ? part[t - off] : 0;
        __syncthreads();
        part[t] += u;
        __syncthreads();
    }
    if (i < NN) {
        const int excl = bpre[blockIdx.x] + part[t] - v;
        rowptr[i] = excl;
        if (i == NN - 1) rowptr[NN] = excl + v;
    }
}

// ---------------- bucket pipeline: hist -> hscan -> binscat -> bcnt -> binfill ----------------
__global__ __launch_bounds__(256) void k_hist(const int* __restrict__ dst,
                                              int* __restrict__ histT) {
    __shared__ int h[NBKT];
    const int tid = threadIdx.x;
    if (tid < NBKT) h[tid] = 0;
    __syncthreads();
    const int base = blockIdx.x * ECH;
    for (int i = base + tid; i < base + ECH; i += 256)
        atomicAdd(&h[(uint)dst[i] / BSTR], 1);
    __syncthreads();
    if (tid < NBKT) histT[tid * CHK + blockIdx.x] = h[tid];
}

__global__ __launch_bounds__(1024) void k_hscan(const int* __restrict__ histT,
                                                int* __restrict__ histS) {
    __shared__ int part[1024];
    const int t = threadIdx.x;
    const int base = t * 16;
    int loc[16];
    int s = 0;
#pragma unroll
    for (int i = 0; i < 16; ++i) {
        loc[i] = histT[base + i];
        s += loc[i];
    }
    part[t] = s;
    __syncthreads();
    for (int off = 1; off < 1024; off <<= 1) {
        int v = (t >= off) ? part[t - off] : 0;
        __syncthreads();
        part[t] += v;
        __syncthreads();
    }
    int run = (t == 0) ? 0 : part[t - 1];
#pragma unroll
    for (int i = 0; i < 16; ++i) {
        histS[base + i] = run;
        run += loc[i];
    }
}

// k_binscat: chunks re-read edges, write (dst, src<<16) to bucket-major mid[]
__global__ __launch_bounds__(256) void k_binscat(const int* __restrict__ src,
                                                 const int* __restrict__ dst,
                                                 const int* __restrict__ histS,
                                                 uint2* __restrict__ mid) {
    __shared__ int cur[NBKT];
    const int tid = threadIdx.x;
    if (tid < NBKT) cur[tid] = histS[tid * CHK + blockIdx.x];
    __syncthreads();
    const int base = blockIdx.x * ECH;
    for (int i = base + tid; i < base + ECH; i += 256) {
        const int s = src[i];
        const int d = dst[i];
        const int p = atomicAdd(&cur[(uint)d / BSTR], 1);
        mid[p] = make_uint2((uint)d, (uint)s << 16);
    }
}

// k_bcnt: per-node degree counts from bucketed mid (replaces global atomic k_deg)
__global__ __launch_bounds__(256) void k_bcnt(const uint2* __restrict__ mid,
                                              const int* __restrict__ histS,
                                              int* __restrict__ cnt) {
    __shared__ int cur[BSTR];
    const int tid = threadIdx.x;
    const int b = blockIdx.x;
    for (int j = tid; j < BSTR; j += 256) cur[j] = 0;
    __syncthreads();
    const int lo = histS[b * CHK];
    const int hi = (b < NBKT - 1) ? histS[(b + 1) * CHK] : NE;
    for (int e = lo + tid; e < hi; e += 256)
        atomicAdd(&cur[mid[e].x - (uint)b * BSTR], 1);
    __syncthreads();
    for (int j = tid; j < BSTR; j += 256) {
        const int idx = b * BSTR + j;
        if (idx < NN) cnt[idx] = cur[j];
    }
}

// k_binfill: one block per bucket; computes norm, scatter confined to ~25 KB csr window
__global__ __launch_bounds__(256) void k_binfill(const uint2* __restrict__ mid,
                                                 const int* __restrict__ histS,
                                                 const int* __restrict__ rowptr,
                                                 const float* __restrict__ dinv,
                                                 uint* __restrict__ csr) {
    __shared__ int cur[BSTR];
    __shared__ float sdv[BSTR];
    const int tid = threadIdx.x;
    const int b = blockIdx.x;
    for (int j = tid; j < BSTR; j += 256) {
        const int idx = b * BSTR + j;
        cur[j] = (idx < NN) ? rowptr[idx] : 0;
        sdv[j] = (idx < NN) ? dinv[idx] : 0.f;
    }
    __syncthreads();
    const int lo = histS[b * CHK];
    const int hi = (b < NBKT - 1) ? histS[(b + 1) * CHK] : NE;
    for (int e = lo + tid; e < hi; e += 256) {
        const uint2 u = mid[e];
        const int j = u.x - (uint)b * BSTR;
        const float norm = dinv[u.y >> 16] * sdv[j];
        const int p = atomicAdd(&cur[j], 1);
        csr[p] = u.y | __half_as_ushort(__float2half(norm));
    }
}

// ---------------- W -> fragment-linear hi/lo bf16 split (once per launch) ----------------
__global__ __launch_bounds__(256) void k_wconv(const float* __restrict__ W,
                                               ushort* __restrict__ Wt,
                                               int K) {
    int i = blockIdx.x * 256 + threadIdx.x;
    if (i < K * C_HID) {
        int k = i >> 7, n = i & 127;  // N = 128
        float w = W[i];
        ushort h = f2bf(w);
        ushort l = f2bf(w - bf2f(h));
        int blk = k >> 6, khalf = (k >> 5) & 1, kq = (k >> 3) & 3, j = k & 7;
        int t = n >> 4, fr = n & 15, lane = kq * 16 + fr;
        size_t off = (size_t)blk * 16384 + (size_t)((khalf * 8 + t) * 64 + lane) * 8 + j;
        Wt[off] = h;
        Wt[off + 8192] = l;
    }
}

// ---------------- split-bf16 MFMA GEMM, BM=32, prefetch-pipelined ----------------
// 4 waves: g = wv>>1 -> rows [bm+g*16, +16); ch = wv&1 -> col tiles [ch*4, ch*4+4)
template <bool IN_RELU_BIAS, bool OUT_BIAS>
__global__ __launch_bounds__(256) void k_gemm_mfma(const float* __restrict__ X,
                                                   const ushort* __restrict__ Wt,
                                                   const float* __restrict__ bin,
                                                   const float* __restrict__ bout,
                                                   const float* __restrict__ dinv,
                                                   ushort* __restrict__ out_main,
                                                   float* __restrict__ out_self,
                                                   int K) {
    __shared__ short8 Bs8[2048];  // 32 KB, one 64-k block of W (hi 16K + lo 16K)

    const int tid = threadIdx.x;
    const int bm = blockIdx.x * 32;
    const int wv = tid >> 6;
    const int lane = tid & 63;
    const int fr = lane & 15;
    const int kq = lane >> 4;
    const int g = wv >> 1;
    const int ch = wv & 1;

    int row = bm + g * 16 + fr;
    if (row >= NN) row = NN - 1;  // clamp (stores guarded)
    const float* xrow = X + (size_t)row * K + kq * 8;
    const short8* Wt8 = (const short8*)Wt;

    f32x4 acc[4];
#pragma unroll
    for (int t = 0; t < 4; ++t) acc[t] = (f32x4){0.f, 0.f, 0.f, 0.f};

    // prologue: load iter-0 A and B
    float4 xa0 = *(const float4*)(xrow);
    float4 xa1 = *(const float4*)(xrow + 4);
    float4 xb0 = *(const float4*)(xrow + 32);
    float4 xb1 = *(const float4*)(xrow + 36);
    short8 tmp[8];
#pragma unroll
    for (int i = 0; i < 8; ++i) tmp[i] = Wt8[i * 256 + tid];

    for (int k0 = 0; k0 < K; k0 += 64) {
        // ---- convert current A to hi/lo bf16 frags ----
        float xv[16] = {xa0.x, xa0.y, xa0.z, xa0.w, xa1.x, xa1.y, xa1.z, xa1.w,
                        xb0.x, xb0.y, xb0.z, xb0.w, xb1.x, xb1.y, xb1.z, xb1.w};
        if (IN_RELU_BIAS) {
            const float* bp = bin + k0 + kq * 8;
            float4 b0 = *(const float4*)(bp);
            float4 b1 = *(const float4*)(bp + 4);
            float4 b2 = *(const float4*)(bp + 32);
            float4 b3 = *(const float4*)(bp + 36);
            const float bb[16] = {b0.x, b0.y, b0.z, b0.w, b1.x, b1.y, b1.z, b1.w,
                                  b2.x, b2.y, b2.z, b2.w, b3.x, b3.y, b3.z, b3.w};
#pragma unroll
            for (int j = 0; j < 16; ++j) xv[j] = fmaxf(xv[j] + bb[j], 0.f);
        }
        union { ushort u[8]; short8 v; } ah0, al0, ah1, al1;
#pragma unroll
        for (int j = 0; j < 8; ++j) {
            uint u = __float_as_uint(xv[j]);
            ah0.u[j] = (ushort)(u >> 16);
            al0.u[j] = (ushort)(__float_as_uint(xv[j] - __uint_as_float(u & 0xffff0000u)) >> 16);
            uint w = __float_as_uint(xv[8 + j]);
            ah1.u[j] = (ushort)(w >> 16);
            al1.u[j] = (ushort)(__float_as_uint(xv[8 + j] - __uint_as_float(w & 0xffff0000u)) >> 16);
        }

        __syncthreads();  // prev iter's Bs readers done
#pragma unroll
        for (int i = 0; i < 8; ++i) Bs8[i * 256 + tid] = tmp[i];
        __syncthreads();  // Bs visible

        // ---- prefetch next iter's A and B while MFMA runs ----
        if (k0 + 64 < K) {
            const float* ap = xrow + k0 + 64;
            xa0 = *(const float4*)(ap);
            xa1 = *(const float4*)(ap + 4);
            xb0 = *(const float4*)(ap + 32);
            xb1 = *(const float4*)(ap + 36);
            const short8* gB = Wt8 + (size_t)((k0 >> 6) + 1) * 2048;
#pragma unroll
            for (int i = 0; i < 8; ++i) tmp[i] = gB[i * 256 + tid];
        }

        // ---- MFMA over this wave's 4 column tiles ----
#pragma unroll
        for (int t = 0; t < 4; ++t) {
            const int tt = ch * 4 + t;
            const short8 bh0 = Bs8[tt * 64 + lane];
            const short8 bl0 = Bs8[1024 + tt * 64 + lane];
            const short8 bh1 = Bs8[(8 + tt) * 64 + lane];
            const short8 bl1 = Bs8[1024 + (8 + tt) * 64 + lane];
            acc[t] = __builtin_amdgcn_mfma_f32_16x16x32_bf16(ah0.v, bh0, acc[t], 0, 0, 0);
            acc[t] = __builtin_amdgcn_mfma_f32_16x16x32_bf16(ah0.v, bl0, acc[t], 0, 0, 0);
            acc[t] = __builtin_amdgcn_mfma_f32_16x16x32_bf16(al0.v, bh0, acc[t], 0, 0, 0);
            acc[t] = __builtin_amdgcn_mfma_f32_16x16x32_bf16(ah1.v, bh1, acc[t], 0, 0, 0);
            acc[t] = __builtin_amdgcn_mfma_f32_16x16x32_bf16(ah1.v, bl1, acc[t], 0, 0, 0);
            acc[t] = __builtin_amdgcn_mfma_f32_16x16x32_bf16(al1.v, bh1, acc[t], 0, 0, 0);
        }
    }

    // ---- epilogue: D(lane,reg): m = bm + g*16 + kq*4 + r, n = (ch*4+t)*16 + fr ----
#pragma unroll
    for (int r = 0; r < 4; ++r) {
        const int m = bm + g * 16 + kq * 4 + r;
        if (m < NN) {
            const float dv = dinv[m];
            const float d2 = dv * dv;
            ushort* om = out_main + (size_t)m * C_HID;
            float* os = out_self + (size_t)m * C_HID;
#pragma unroll
            for (int t = 0; t < 4; ++t) {
                const int n = (ch * 4 + t) * 16 + fr;
                const float v = acc[t][r];
                om[n] = f2bf(v);
                os[n] = v * d2 + (OUT_BIAS ? bout[n] : 0.f);
            }
        }
    }
}

// ---------------- CSR gather: out[d] = init(out[d]) + sum_e bf16(h[src_e])*norm_e ----------------
__global__ __launch_bounds__(256) void k_gather(const ushort* __restrict__ h,
                                                const int* __restrict__ rowptr,
                                                const uint* __restrict__ csr,
                                                float* __restrict__ out) {
    const int tid = threadIdx.x;
    const int node = blockIdx.x * 8 + (tid >> 5);
    if (node >= NN) return;
    const int lane = tid & 31;
    const int c = lane * 4;
    const int beg = rowptr[node];
    const int end = rowptr[node + 1];

    float4 acc = *(const float4*)(out + (size_t)node * C_HID + c);  // self-loop init

    for (int j0 = beg; j0 < end; j0 += 32) {
        const int n = end - j0;
        uint myE = 0;
        if (lane < n) myE = csr[j0 + lane];
        const int m = n < 32 ? n : 32;
        int jj = 0;
        for (; jj + 4 <= m; jj += 4) {
            const uint e0 = (uint)__shfl((int)myE, jj + 0, 32);
            const uint e1 = (uint)__shfl((int)myE, jj + 1, 32);
            const uint e2 = (uint)__shfl((int)myE, jj + 2, 32);
            const uint e3 = (uint)__shfl((int)myE, jj + 3, 32);
            const us4 u0 = *(const us4*)(h + (size_t)(e0 >> 16) * C_HID + c);
            const us4 u1 = *(const us4*)(h + (size_t)(e1 >> 16) * C_HID + c);
            const us4 u2 = *(const us4*)(h + (size_t)(e2 >> 16) * C_HID + c);
            const us4 u3 = *(const us4*)(h + (size_t)(e3 >> 16) * C_HID + c);
            const float n0 = __half2float(__ushort_as_half((ushort)(e0 & 0xffffu)));
            const float n1 = __half2float(__ushort_as_half((ushort)(e1 & 0xffffu)));
            const float n2 = __half2float(__ushort_as_half((ushort)(e2 & 0xffffu)));
            const float n3 = __half2float(__ushort_as_half((ushort)(e3 & 0xffffu)));
            acc.x = fmaf(bf2f(u0[0]), n0, acc.x);
            acc.y = fmaf(bf2f(u0[1]), n0, acc.y);
            acc.z = fmaf(bf2f(u0[2]), n0, acc.z);
            acc.w = fmaf(bf2f(u0[3]), n0, acc.w);
            acc.x = fmaf(bf2f(u1[0]), n1, acc.x);
            acc.y = fmaf(bf2f(u1[1]), n1, acc.y);
            acc.z = fmaf(bf2f(u1[2]), n1, acc.z);
            acc.w = fmaf(bf2f(u1[3]), n1, acc.w);
            acc.x = fmaf(bf2f(u2[0]), n2, acc.x);
            acc.y = fmaf(bf2f(u2[1]), n2, acc.y);
            acc.z = fmaf(bf2f(u2[2]), n2, acc.z);
            acc.w = fmaf(bf2f(u2[3]), n2, acc.w);
            acc.x = fmaf(bf2f(u3[0]), n3, acc.x);
            acc.y = fmaf(bf2f(u3[1]), n3, acc.y);
            acc.z = fmaf(bf2f(u3[2]), n3, acc.z);
            acc.w = fmaf(bf2f(u3[3]), n3, acc.w);
        }
        for (; jj < m; ++jj) {
            const uint ev = (uint)__shfl((int)myE, jj, 32);
            const us4 u = *(const us4*)(h + (size_t)(ev >> 16) * C_HID + c);
            const float nw = __half2float(__ushort_as_half((ushort)(ev & 0xffffu)));
            acc.x = fmaf(bf2f(u[0]), nw, acc.x);
            acc.y = fmaf(bf2f(u[1]), nw, acc.y);
            acc.z = fmaf(bf2f(u[2]), nw, acc.z);
            acc.w = fmaf(bf2f(u[3]), nw, acc.w);
        }
    }
    *(float4*)(out + (size_t)node * C_HID + c) = acc;
}

extern "C" void kernel_launch(void* const* d_in, const int* in_sizes, int n_in,
                              void* d_out, int out_size, void* d_ws, size_t ws_size,
                              hipStream_t stream) {
    const float* x = (const float*)d_in[0];
    const int* ei = (const int*)d_in[1];
    const float* W1 = (const float*)d_in[2];
    const float* b1 = (const float*)d_in[3];
    const float* W2 = (const float*)d_in[4];
    const float* b2 = (const float*)d_in[5];
    float* out = (float*)d_out;

    const int* src = ei;
    const int* dst = ei + NE;

    // workspace layout (4-byte units)
    int* cnt = (int*)d_ws;                       // 50048
    int* rowptr = cnt + 50048;                   // 50064 (NN+1)
    float* dinv = (float*)(rowptr + 50064);      // 50048
    int* bsum = (int*)(dinv + 50048);            // 256
    int* bpre = bsum + 256;                      // 256
    int* histT = bpre + 256;                     // 16384
    int* histS = histT + 16384;                  // 16384
    ushort* Wt1 = (ushort*)(histS + 16384);      // 98304 shorts (frag-linear hi+lo)
    ushort* Wt2 = Wt1 + 98304;                   // 32768 shorts
    uint* csr = (uint*)(Wt2 + 32768);            // NE uints
    uint2* mid = (uint2*)(csr + NE);             // NE uint2
    ushort* A_bf = (ushort*)(mid + NE);          // NN*128 shorts (h bf16)
    float* B = (float*)(A_bf + (size_t)NN * C_HID);  // NN*128 fp32 (agg buffer)

    k_wconv<<<(C_IN * C_HID + 255) / 256, 256, 0, stream>>>(W1, Wt1, C_IN);
    k_wconv<<<(C_HID * C_HID + 255) / 256, 256, 0, stream>>>(W2, Wt2, C_HID);
    k_hist<<<CHK, 256, 0, stream>>>(dst, histT);
    k_hscan<<<1, 1024, 0, stream>>>(histT, histS);
    k_binscat<<<CHK, 256, 0, stream>>>(src, dst, histS, mid);
    k_bcnt<<<NBKT, 256, 0, stream>>>(mid, histS, cnt);
    k_dinv<<<NB, 256, 0, stream>>>(cnt, dinv);
    k_bsum<<<NB, 256, 0, stream>>>(cnt, bsum);
    k_sbs<<<1, 256, 0, stream>>>(bsum, bpre);
    k_write<<<NB, 256, 0, stream>>>(cnt, bpre, rowptr);
    k_binfill<<<NBKT, 256, 0, stream>>>(mid, histS, rowptr, dinv, csr);

    const int gblocks = (NN + 31) / 32;
    const int agblocks = (NN + 7) / 8;
    // layer 1: h1 = x@W1 -> A_bf (bf16) ;  B = h1*dinv^2 (fp32 self-loop init)
    k_gemm_mfma<false, false><<<gblocks, 256, 0, stream>>>(x, Wt1, nullptr, nullptr, dinv, A_bf, B, C_IN);
    // B += gather(h1)
    k_gather<<<agblocks, 256, 0, stream>>>(A_bf, rowptr, csr, B);
    // layer 2: h2 = relu(B + b1)@W2 -> A_bf ; out = h2*dinv^2 + b2 (self-loop init)
    k_gemm_mfma<true, true><<<gblocks, 256, 0, stream>>>(B, Wt2, b1, b2, dinv, A_bf, out, C_HID);
    // out += gather(h2)
    k_gather<<<agblocks, 256, 0, stream>>>(A_bf, rowptr, csr, out);
}